// Round 1
// baseline (172.778 us; speedup 1.0000x reference)
//
#include <hip/hip_runtime.h>

// EndEffectorLoss R8: latency-batched staging + 2-stage register prefetch + b128 LDS.
//
// R7 diagnosis: VALUBusy 19%, HBM 22%, occupancy 18%, conflicts 1.5% -> pure
// latency serialization. Occupancy is structurally capped (2048 waves total =
// 8 waves/CU), so the fix is the dependency chain: R7's stageP interleaved
// load->ds_write per float4, serializing ~12 global latencies per stage.
// R8: each stage's 9 float4 global loads issue as ONE batch ~1.5 FK-phases
// ahead of their ds_writes (register double-buffer bA/bB), LDS is written and
// read as float4 (b128) with odd-16B row strides (7 resp. 5 float4 -> lane
// strides 112B/80B, conflict-free). Per stage: 9 loads + 9 ds_write_b128 +
// 9 ds_read_b128 (was 12 loads + 36 ds_write_b32 + 36 ds_read_b32).
// VGPR budget is free up to 256 (grid caps at 2 waves/SIMD) -> __launch_bounds__(256,2).

struct V3 { float x, y, z; };
struct M3 { float m[3][3]; };   // row r = basis vector b_r (row-stacked)
struct FK { M3 o; V3 p; };

__device__ __forceinline__ V3 matvec(const M3& A, const V3& v) {
    return { A.m[0][0]*v.x + A.m[0][1]*v.y + A.m[0][2]*v.z,
             A.m[1][0]*v.x + A.m[1][1]*v.y + A.m[1][2]*v.z,
             A.m[2][0]*v.x + A.m[2][1]*v.y + A.m[2][2]*v.z };
}

__device__ __forceinline__ M3 matmul(const M3& A, const M3& B) {
    M3 C;
#pragma unroll
    for (int i = 0; i < 3; i++)
#pragma unroll
        for (int j = 0; j < 3; j++)
            C.m[i][j] = A.m[i][0]*B.m[0][j] + A.m[i][1]*B.m[1][j] + A.m[i][2]*B.m[2][j];
    return C;
}

// Gram-Schmidt from 6 scalars (matches jnp reference, f32).
__device__ __forceinline__ M3 rot6d(float v0, float v1, float v2,
                                    float v3, float v4, float v5) {
    float n1 = v0*v0 + v1*v1 + v2*v2;
    float r1 = 1.0f / sqrtf(n1);
    V3 b1 = { v0*r1, v1*r1, v2*r1 };
    float d = b1.x*v3 + b1.y*v4 + b1.z*v5;
    V3 u = { v3 - d*b1.x, v4 - d*b1.y, v5 - d*b1.z };
    float n2 = u.x*u.x + u.y*u.y + u.z*u.z;
    float r2 = 1.0f / sqrtf(n2);
    V3 b2 = { u.x*r2, u.y*r2, u.z*r2 };
    V3 b3 = { b1.y*b2.z - b1.z*b2.y, b1.z*b2.x - b1.x*b2.z, b1.x*b2.y - b1.y*b2.x };
    M3 R;
    R.m[0][0]=b1.x; R.m[0][1]=b1.y; R.m[0][2]=b1.z;
    R.m[1][0]=b2.x; R.m[1][1]=b2.y; R.m[1][2]=b2.z;
    R.m[2][0]=b3.x; R.m[2][1]=b3.y; R.m[2][2]=b3.z;
    return R;
}

__device__ __forceinline__ FK fk_step(float a0,float a1,float a2,float a3,float a4,float a5,
                                      float ox,float oy,float oz, const FK& par) {
    V3 t = matvec(par.o, {ox, oy, oz});
    FK s;
    s.p = { par.p.x + t.x, par.p.y + t.y, par.p.z + t.z };
    s.o = matmul(par.o, rot6d(a0, a1, a2, a3, a4, a5));
    return s;
}

__device__ __forceinline__ V3 fk_end(float ox, float oy, float oz, const FK& par) {
    V3 t = matvec(par.o, {ox, oy, oz});
    return { par.p.x + t.x, par.p.y + t.y, par.p.z + t.z };
}

#define PSTR 7   // pose row stride, float4 units (6 data + 1 pad; odd -> conflict-free b128)
#define OSTR 5   // off  row stride, float4 units (3 data + 2 pad; odd)

// Register staging buffer: one FK-stage of data for this lane's wave (36 VGPRs).
struct SBuf { float4 p[6]; float4 o[3]; };

// Issue all 9 global float4 loads of stage st (frame-transposed: lane i takes
// the i-th float4 of the wave's concatenated frame-chunks -> coalesced).
// All addresses 16B-aligned: pose byte off = f*576 + st*96 + c*16;
// off byte off = f*288 + st*48 + c*16.
__device__ __forceinline__ void load_stage(SBuf& b, const float* __restrict__ P,
                                           const float* __restrict__ O,
                                           int lane, int st) {
#pragma unroll
    for (int k = 0; k < 6; k++) {
        int idx = lane + 64*k, f = idx/6, c = idx - 6*f;
        b.p[k] = *(const float4*)(P + f*144 + st*24 + c*4);
    }
#pragma unroll
    for (int k = 0; k < 3; k++) {
        int idx = lane + 64*k, f = idx/3, c = idx - 3*f;
        b.o[k] = *(const float4*)(O + f*72 + st*12 + c*4);
    }
}

// 9 ds_write_b128 into the wave-private slice (in-order DS per wave: these
// follow the previous stage's ds_reads in issue order -> WAR-safe, no barrier).
__device__ __forceinline__ void write_stage(const SBuf& b, float4* sp, float4* so, int lane) {
#pragma unroll
    for (int k = 0; k < 6; k++) {
        int idx = lane + 64*k, f = idx/6, c = idx - 6*f;
        sp[f*PSTR + c] = b.p[k];
    }
#pragma unroll
    for (int k = 0; k < 3; k++) {
        int idx = lane + 64*k, f = idx/3, c = idx - 3*f;
        so[f*OSTR + c] = b.o[k];
    }
}

// Read this lane's full stage (24 pose floats + 12 off floats) as 9 b128.
#define READQ  q0 = rp[0]; q1 = rp[1]; q2 = rp[2]; q3 = rp[3]; q4 = rp[4]; q5 = rp[5]; \
               r0 = ro[0]; r1 = ro[1]; r2 = ro[2];
// Joint jj in {0..3} of a stage: pose floats 6jj..6jj+5, off floats 3jj..3jj+2.
#define J0ROT  q0.x,q0.y,q0.z,q0.w,q1.x,q1.y
#define J1ROT  q1.z,q1.w,q2.x,q2.y,q2.z,q2.w
#define J2ROT  q3.x,q3.y,q3.z,q3.w,q4.x,q4.y
#define J3ROT  q4.z,q4.w,q5.x,q5.y,q5.z,q5.w
#define J0OFF  r0.x,r0.y,r0.z
#define J1OFF  r0.w,r1.x,r1.y
#define J2OFF  r1.z,r1.w,r2.x
#define J3OFF  r2.y,r2.z,r2.w

__global__ __launch_bounds__(256, 2)
void ee_loss_kernel(const float* __restrict__ poseA, const float* __restrict__ poseB,
                    const float* __restrict__ offA,  const float* __restrict__ offB,
                    const float* __restrict__ tA,    const float* __restrict__ tB,
                    float* __restrict__ out, float inv_count) {
    __shared__ float4 s_pose[4][64 * PSTR];   // 28.0 KB (wave-private slices)
    __shared__ float4 s_off [4][64 * OSTR];   // 20.0 KB
    __shared__ float s_eeB[128][15];          // 7.5 KB (stride 15, coprime 32)
    __shared__ float s_inv[6];
    __shared__ float s_d[15];
    __shared__ float s_part[2];

    const int tid  = threadIdx.x;
    const int wid  = tid >> 6;            // 0..3
    const int lane = tid & 63;
    const bool isB = wid & 1;             // waves 1,3 -> pose B
    const int fg   = wid >> 1;            // frame-group 0/1 within block
    const int fl   = fg * 64 + lane;      // frame-local 0..127
    const long long f0 = (long long)blockIdx.x * 128 + fg * 64;

    const float* __restrict__ P = (isB ? poseB : poseA) + f0 * 144;
    const float* __restrict__ O = (isB ? offB  : offA ) + f0 * 72;

    float4* sp = s_pose[wid];             // this wave's slices (NO __restrict__:
    float4* so = s_off[wid];              // rp/ro alias sp/so by design)
    const float4* rp = sp + lane * PSTR;
    const float4* ro = so + lane * OSTR;

    // ---- prologue: issue stages 0 and 1 (18 loads in flight) ----
    SBuf bA, bB;
    load_stage(bA, P, O, lane, 0);
    load_stage(bB, P, O, lane, 1);

    // t_pose-derived constants (wave 0 lanes only; overlaps in-flight loads;
    // consumed after the single barrier at the end)
    if (tid < 6) {
        const float* tp = (tid < 3) ? tA : tB;
        int ax = (tid < 3) ? tid : tid - 3;
        float mn = tp[ax], mx = mn;
#pragma unroll
        for (int j = 1; j < 24; j++) {
            float v = tp[j*3 + ax];
            mn = fminf(mn, v); mx = fmaxf(mx, v);
        }
        s_inv[tid] = 1.0f / (mx - mn);
    }
    if (tid < 15) {
        const int EE[5] = {10, 11, 15, 22, 23};
        int e = tid / 3, ax = tid - 3*e;
        int j = EE[e];
        float mnA = tA[ax], mxA = mnA, mnB = tB[ax], mxB = mnB;
#pragma unroll
        for (int k = 1; k < 24; k++) {
            float a = tA[k*3 + ax], b = tB[k*3 + ax];
            mnA = fminf(mnA, a); mxA = fmaxf(mxA, a);
            mnB = fminf(mnB, b); mxB = fmaxf(mxB, b);
        }
        s_d[tid] = tB[j*3 + ax]/(mxB - mnB) - tA[j*3 + ax]/(mxA - mnA);
    }

    write_stage(bA, sp, so, lane);        // st0 -> LDS (waits only bA's 9 loads)

    float4 q0, q1, q2, q3, q4, q5, r0, r1, r2;

    // ---- stage 0: joints 0..3 ----
    READQ;
    load_stage(bA, P, O, lane, 2);        // prefetch st2 (covered by FK0+FK1)
    FK s0; s0.o = rot6d(J0ROT); s0.p = { r0.x, r0.y, r0.z };
    FK s1 = fk_step(J1ROT, J1OFF, s0);
    FK s2 = fk_step(J2ROT, J2OFF, s0);
    FK s3 = fk_step(J3ROT, J3OFF, s0);
    write_stage(bB, sp, so, lane);        // st1 -> LDS

    // ---- stage 1: joints 4..7 ----
    READQ;
    load_stage(bB, P, O, lane, 3);
    FK s4 = fk_step(J0ROT, J0OFF, s1);
    FK s5 = fk_step(J1ROT, J1OFF, s2);
    FK s6 = fk_step(J2ROT, J2OFF, s3);
    FK s7 = fk_step(J3ROT, J3OFF, s4);
    write_stage(bA, sp, so, lane);        // st2 -> LDS

    // ---- stage 2: joints 8..11 (10,11 end sites) ----
    READQ;
    load_stage(bA, P, O, lane, 4);
    FK s8 = fk_step(J0ROT, J0OFF, s5);
    FK s9 = fk_step(J1ROT, J1OFF, s6);
    V3 e10 = fk_end(J2OFF, s7);
    V3 e11 = fk_end(J3OFF, s8);
    write_stage(bB, sp, so, lane);        // st3 -> LDS

    // ---- stage 3: joints 12..15 (15 end site) ----
    READQ;
    load_stage(bB, P, O, lane, 5);
    FK s12 = fk_step(J0ROT, J0OFF, s9);
    FK s13 = fk_step(J1ROT, J1OFF, s9);
    FK s14 = fk_step(J2ROT, J2OFF, s9);
    V3 e15 = fk_end(J3OFF, s12);
    write_stage(bA, sp, so, lane);        // st4 -> LDS

    // ---- stage 4: joints 16..19 ----
    READQ;
    FK s16 = fk_step(J0ROT, J0OFF, s13);
    FK s17 = fk_step(J1ROT, J1OFF, s14);
    FK s18 = fk_step(J2ROT, J2OFF, s16);
    FK s19 = fk_step(J3ROT, J3OFF, s17);
    write_stage(bB, sp, so, lane);        // st5 -> LDS

    // ---- stage 5: joints 20..23 (22,23 end sites) ----
    READQ;
    FK s20 = fk_step(J0ROT, J0OFF, s18);
    FK s21 = fk_step(J1ROT, J1OFF, s19);
    V3 e22 = fk_end(J2OFF, s20);
    V3 e23 = fk_end(J3OFF, s21);

    // ---- exchange B results (one barrier), diff on A threads, reduce ----
    if (isB) {
        s_eeB[fl][ 0] = e10.x; s_eeB[fl][ 1] = e10.y; s_eeB[fl][ 2] = e10.z;
        s_eeB[fl][ 3] = e11.x; s_eeB[fl][ 4] = e11.y; s_eeB[fl][ 5] = e11.z;
        s_eeB[fl][ 6] = e15.x; s_eeB[fl][ 7] = e15.y; s_eeB[fl][ 8] = e15.z;
        s_eeB[fl][ 9] = e22.x; s_eeB[fl][10] = e22.y; s_eeB[fl][11] = e22.z;
        s_eeB[fl][12] = e23.x; s_eeB[fl][13] = e23.y; s_eeB[fl][14] = e23.z;
    }
    __syncthreads();

    float local = 0.0f;
    if (!isB) {
        const float iax = s_inv[0], iay = s_inv[1], iaz = s_inv[2];
        const float ibx = s_inv[3], iby = s_inv[4], ibz = s_inv[5];
        const float* eb = s_eeB[fl];
        float t0  = e10.x*iax - eb[ 0]*ibx + s_d[ 0];
        float t1  = e10.y*iay - eb[ 1]*iby + s_d[ 1];
        float t2  = e10.z*iaz - eb[ 2]*ibz + s_d[ 2];
        float t3  = e11.x*iax - eb[ 3]*ibx + s_d[ 3];
        float t4  = e11.y*iay - eb[ 4]*iby + s_d[ 4];
        float t5  = e11.z*iaz - eb[ 5]*ibz + s_d[ 5];
        float t6  = e15.x*iax - eb[ 6]*ibx + s_d[ 6];
        float t7  = e15.y*iay - eb[ 7]*iby + s_d[ 7];
        float t8  = e15.z*iaz - eb[ 8]*ibz + s_d[ 8];
        float t9  = e22.x*iax - eb[ 9]*ibx + s_d[ 9];
        float t10 = e22.y*iay - eb[10]*iby + s_d[10];
        float t11 = e22.z*iaz - eb[11]*ibz + s_d[11];
        float t12 = e23.x*iax - eb[12]*ibx + s_d[12];
        float t13 = e23.y*iay - eb[13]*iby + s_d[13];
        float t14 = e23.z*iaz - eb[14]*ibz + s_d[14];
        local = ((t0*t0 + t1*t1) + (t2*t2 + t3*t3) + (t4*t4 + t5*t5) +
                 (t6*t6 + t7*t7) + (t8*t8 + t9*t9) + (t10*t10 + t11*t11) +
                 (t12*t12 + t13*t13) + t14*t14) * inv_count;
#pragma unroll
        for (int off = 32; off > 0; off >>= 1)
            local += __shfl_down(local, off, 64);
        if (lane == 0) s_part[fg] = local;
    }
    __syncthreads();
    if (tid == 0) atomicAdd(out, s_part[0] + s_part[1]);
}

extern "C" void kernel_launch(void* const* d_in, const int* in_sizes, int n_in,
                              void* d_out, int out_size, void* d_ws, size_t ws_size,
                              hipStream_t stream) {
    const float* poseA = (const float*)d_in[0];
    const float* poseB = (const float*)d_in[1];
    const float* offA  = (const float*)d_in[2];
    const float* offB  = (const float*)d_in[3];
    const float* tA    = (const float*)d_in[4];
    const float* tB    = (const float*)d_in[5];
    float* out = (float*)d_out;

    const int F = in_sizes[0] / 144;          // 65536
    const int blocks = F / 128;               // 512 = 2 blocks/CU exactly
    const float inv_count = 1.0f / ((float)F * 15.0f);

    hipMemsetAsync(out, 0, sizeof(float), stream);
    ee_loss_kernel<<<blocks, 256, 0, stream>>>(poseA, poseB, offA, offB, tA, tB,
                                               out, inv_count);
}

// Round 2
// 149.217 us; speedup vs baseline: 1.1579x; 1.1579x over previous
//
#include <hip/hip_runtime.h>

// EndEffectorLoss R9: async global->LDS DMA staging (zero-VGPR) + counted vmcnt pipeline.
//
// R8 post-mortem: register double-buffer (2x36 VGPR SBuf) caused scratch spills
// (WRITE_SIZE 16B -> 52MB, FETCH +48MB round-trip) -> 43 -> 69us. The pipeline
// idea was right; paying in VGPRs was wrong.
// R9: __builtin_amdgcn_global_load_lds(.,.,16,0,0) stages each FK stage's
// 9 float4-chunks straight into LDS (no VGPRs, counted by vmcnt). LDS dest is
// lane-linear (HW: base + lane*16), so layout is packed [64 frames][6 float4]
// pose rows / [64][3] off rows per wave per buffer. Double-buffered (2 stages
// in flight); in the loop we wait vmcnt(9) = "current stage landed, next still
// flying" -- never drain to 0 until the last stage (T4 idiom). Prefetch is
// issued ~2 FK phases ahead (~2000cy) > HBM latency. lgkmcnt(0) between a
// buffer's ds_reads and its reuse as DMA dest (WAR guard). s_eeB aliases s_off
// (post-FK, behind a barrier) to keep LDS at 73.8KB -> 2 blocks/CU, 8 waves/CU.

struct V3 { float x, y, z; };
struct M3 { float m[3][3]; };   // row r = basis vector b_r (row-stacked)
struct FK { M3 o; V3 p; };

__device__ __forceinline__ V3 matvec(const M3& A, const V3& v) {
    return { A.m[0][0]*v.x + A.m[0][1]*v.y + A.m[0][2]*v.z,
             A.m[1][0]*v.x + A.m[1][1]*v.y + A.m[1][2]*v.z,
             A.m[2][0]*v.x + A.m[2][1]*v.y + A.m[2][2]*v.z };
}

__device__ __forceinline__ M3 matmul(const M3& A, const M3& B) {
    M3 C;
#pragma unroll
    for (int i = 0; i < 3; i++)
#pragma unroll
        for (int j = 0; j < 3; j++)
            C.m[i][j] = A.m[i][0]*B.m[0][j] + A.m[i][1]*B.m[1][j] + A.m[i][2]*B.m[2][j];
    return C;
}

// Gram-Schmidt from 6 scalars (matches jnp reference, f32).
__device__ __forceinline__ M3 rot6d(float v0, float v1, float v2,
                                    float v3, float v4, float v5) {
    float n1 = v0*v0 + v1*v1 + v2*v2;
    float r1 = 1.0f / sqrtf(n1);
    V3 b1 = { v0*r1, v1*r1, v2*r1 };
    float d = b1.x*v3 + b1.y*v4 + b1.z*v5;
    V3 u = { v3 - d*b1.x, v4 - d*b1.y, v5 - d*b1.z };
    float n2 = u.x*u.x + u.y*u.y + u.z*u.z;
    float r2 = 1.0f / sqrtf(n2);
    V3 b2 = { u.x*r2, u.y*r2, u.z*r2 };
    V3 b3 = { b1.y*b2.z - b1.z*b2.y, b1.z*b2.x - b1.x*b2.z, b1.x*b2.y - b1.y*b2.x };
    M3 R;
    R.m[0][0]=b1.x; R.m[0][1]=b1.y; R.m[0][2]=b1.z;
    R.m[1][0]=b2.x; R.m[1][1]=b2.y; R.m[1][2]=b2.z;
    R.m[2][0]=b3.x; R.m[2][1]=b3.y; R.m[2][2]=b3.z;
    return R;
}

__device__ __forceinline__ FK fk_step(float a0,float a1,float a2,float a3,float a4,float a5,
                                      float ox,float oy,float oz, const FK& par) {
    V3 t = matvec(par.o, {ox, oy, oz});
    FK s;
    s.p = { par.p.x + t.x, par.p.y + t.y, par.p.z + t.z };
    s.o = matmul(par.o, rot6d(a0, a1, a2, a3, a4, a5));
    return s;
}

__device__ __forceinline__ V3 fk_end(float ox, float oy, float oz, const FK& par) {
    V3 t = matvec(par.o, {ox, oy, oz});
    return { par.p.x + t.x, par.p.y + t.y, par.p.z + t.z };
}

// Async 16B global->LDS DMA. LDS dest must be wave-uniform; HW adds lane*16.
#define GLDS16(gp, lp) __builtin_amdgcn_global_load_lds( \
    (const __attribute__((address_space(1))) void*)(gp), \
    (__attribute__((address_space(3))) void*)(lp), 16, 0, 0)

// Counted waits; sched_barrier pins ordering (guide rule #18).
#define VWAIT(n) do { asm volatile("s_waitcnt vmcnt(" #n ")" ::: "memory"); \
                      __builtin_amdgcn_sched_barrier(0); } while (0)
#define LWAIT0()  do { asm volatile("s_waitcnt lgkmcnt(0)" ::: "memory"); \
                      __builtin_amdgcn_sched_barrier(0); } while (0)

// Issue one FK stage's 9 DMA ops: pose 6 chunks (64x16B each), off 3 chunks.
// Chunk k of pose: LDS float4 index lane+64k holds global element idx=lane+64k
// -> (f=idx/6, c=idx%6) -> packed [64][6] float4 rows (96B/frame). Off: [64][3].
__device__ __forceinline__ void stage(const float* __restrict__ P,
                                      const float* __restrict__ O,
                                      const int* pOfs, const int* oOfs,
                                      float4* pbuf, float4* obuf, int st) {
#pragma unroll
    for (int k = 0; k < 6; k++)
        GLDS16(P + st*24 + pOfs[k], pbuf + 64*k);
#pragma unroll
    for (int k = 0; k < 3; k++)
        GLDS16(O + st*12 + oOfs[k], obuf + 64*k);
}

// Read this lane's full stage (24 pose floats + 12 off floats) as 9 b128.
#define READQ(pb, ob) \
    q0 = (pb)[0]; q1 = (pb)[1]; q2 = (pb)[2]; q3 = (pb)[3]; q4 = (pb)[4]; q5 = (pb)[5]; \
    r0 = (ob)[0]; r1 = (ob)[1]; r2 = (ob)[2];
// Joint jj in {0..3} of a stage: pose floats 6jj..6jj+5, off floats 3jj..3jj+2.
#define J0ROT  q0.x,q0.y,q0.z,q0.w,q1.x,q1.y
#define J1ROT  q1.z,q1.w,q2.x,q2.y,q2.z,q2.w
#define J2ROT  q3.x,q3.y,q3.z,q3.w,q4.x,q4.y
#define J3ROT  q4.z,q4.w,q5.x,q5.y,q5.z,q5.w
#define J0OFF  r0.x,r0.y,r0.z
#define J1OFF  r0.w,r1.x,r1.y
#define J2OFF  r1.z,r1.w,r2.x
#define J3OFF  r2.y,r2.z,r2.w

__global__ __launch_bounds__(256)
void ee_loss_kernel(const float* __restrict__ poseA, const float* __restrict__ poseB,
                    const float* __restrict__ offA,  const float* __restrict__ offB,
                    const float* __restrict__ tA,    const float* __restrict__ tB,
                    float* __restrict__ out, float inv_count) {
    __shared__ float4 s_pose[4][2][64*6];   // 48.0 KB: [wave][buf][frame*6+c]
    __shared__ float4 s_off [4][2][64*3];   // 24.0 KB: [wave][buf][frame*3+c]
    __shared__ float s_inv[6];
    __shared__ float s_d[15];
    __shared__ float s_part[2];
    // eeB exchange reuses s_off AFTER all FK reads, behind a barrier (7.5KB<24KB).
    float* s_eeB = (float*)&s_off[0][0][0];

    const int tid  = threadIdx.x;
    const int wid  = tid >> 6;            // 0..3
    const int lane = tid & 63;
    const bool isB = wid & 1;             // waves 1,3 -> pose B
    const int fg   = wid >> 1;            // frame-group 0/1 within block
    const int fl   = fg * 64 + lane;      // frame-local 0..127
    const long long f0 = (long long)blockIdx.x * 128 + fg * 64;

    const float* __restrict__ P = (isB ? poseB : poseA) + f0 * 144;
    const float* __restrict__ O = (isB ? offB  : offA ) + f0 * 72;

    float4* pb0 = &s_pose[wid][0][0];
    float4* pb1 = &s_pose[wid][1][0];
    float4* ob0 = &s_off[wid][0][0];
    float4* ob1 = &s_off[wid][1][0];
    const float4* rp0 = pb0 + lane * 6;
    const float4* rp1 = pb1 + lane * 6;
    const float4* ro0 = ob0 + lane * 3;
    const float4* ro1 = ob1 + lane * 3;

    // ---- t_pose constants FIRST (their vmcnt waits must not drain prefetch) ----
    if (tid < 6) {
        const float* tp = (tid < 3) ? tA : tB;
        int ax = (tid < 3) ? tid : tid - 3;
        float mn = tp[ax], mx = mn;
#pragma unroll
        for (int j = 1; j < 24; j++) {
            float v = tp[j*3 + ax];
            mn = fminf(mn, v); mx = fmaxf(mx, v);
        }
        s_inv[tid] = 1.0f / (mx - mn);
    }
    if (tid < 15) {
        const int EE[5] = {10, 11, 15, 22, 23};
        int e = tid / 3, ax = tid - 3*e;
        int j = EE[e];
        float mnA = tA[ax], mxA = mnA, mnB = tB[ax], mxB = mnB;
#pragma unroll
        for (int k = 1; k < 24; k++) {
            float a = tA[k*3 + ax], b = tB[k*3 + ax];
            mnA = fminf(mnA, a); mxA = fmaxf(mxA, a);
            mnB = fminf(mnB, b); mxB = fmaxf(mxB, b);
        }
        s_d[tid] = tB[j*3 + ax]/(mxB - mnB) - tA[j*3 + ax]/(mxA - mnA);
    }

    // Per-lane global float-offsets of this lane's 9 chunks (stage-invariant).
    int pOfs[6], oOfs[3];
#pragma unroll
    for (int k = 0; k < 6; k++) {
        int idx = lane + 64*k, f = idx/6, c = idx - 6*f;
        pOfs[k] = f*144 + c*4;
    }
#pragma unroll
    for (int k = 0; k < 3; k++) {
        int idx = lane + 64*k, f = idx/3, c = idx - 3*f;
        oOfs[k] = f*72 + c*4;
    }

    // ---- prologue: 2 stages in flight ----
    stage(P, O, pOfs, oOfs, pb0, ob0, 0);
    stage(P, O, pOfs, oOfs, pb1, ob1, 1);

    float4 q0, q1, q2, q3, q4, q5, r0, r1, r2;

    // ---- stage 0 (joints 0..3) ----
    VWAIT(9);                              // st0 landed, st1 flying
    READQ(rp0, ro0);
    LWAIT0();                              // reads done -> buf0 reusable (WAR)
    stage(P, O, pOfs, oOfs, pb0, ob0, 2);
    FK s0; s0.o = rot6d(J0ROT); s0.p = { r0.x, r0.y, r0.z };
    FK s1 = fk_step(J1ROT, J1OFF, s0);
    FK s2 = fk_step(J2ROT, J2OFF, s0);
    FK s3 = fk_step(J3ROT, J3OFF, s0);

    // ---- stage 1 (joints 4..7) ----
    VWAIT(9);                              // st1 landed, st2 flying
    READQ(rp1, ro1);
    LWAIT0();
    stage(P, O, pOfs, oOfs, pb1, ob1, 3);
    FK s4 = fk_step(J0ROT, J0OFF, s1);
    FK s5 = fk_step(J1ROT, J1OFF, s2);
    FK s6 = fk_step(J2ROT, J2OFF, s3);
    FK s7 = fk_step(J3ROT, J3OFF, s4);

    // ---- stage 2 (joints 8..11; 10,11 end sites) ----
    VWAIT(9);                              // st2 landed, st3 flying
    READQ(rp0, ro0);
    LWAIT0();
    stage(P, O, pOfs, oOfs, pb0, ob0, 4);
    FK s8 = fk_step(J0ROT, J0OFF, s5);
    FK s9 = fk_step(J1ROT, J1OFF, s6);
    V3 e10 = fk_end(J2OFF, s7);
    V3 e11 = fk_end(J3OFF, s8);

    // ---- stage 3 (joints 12..15; 15 end site) ----
    VWAIT(9);                              // st3 landed, st4 flying
    READQ(rp1, ro1);
    LWAIT0();
    stage(P, O, pOfs, oOfs, pb1, ob1, 5);
    FK s12 = fk_step(J0ROT, J0OFF, s9);
    FK s13 = fk_step(J1ROT, J1OFF, s9);
    FK s14 = fk_step(J2ROT, J2OFF, s9);
    V3 e15 = fk_end(J3OFF, s12);

    // ---- stage 4 (joints 16..19) ----
    VWAIT(9);                              // st4 landed, st5 flying
    READQ(rp0, ro0);
    FK s16 = fk_step(J0ROT, J0OFF, s13);
    FK s17 = fk_step(J1ROT, J1OFF, s14);
    FK s18 = fk_step(J2ROT, J2OFF, s16);
    FK s19 = fk_step(J3ROT, J3OFF, s17);

    // ---- stage 5 (joints 20..23; 22,23 end sites) ----
    VWAIT(0);                              // st5 landed (only drain-to-0 point)
    READQ(rp1, ro1);
    FK s20 = fk_step(J0ROT, J0OFF, s18);
    FK s21 = fk_step(J1ROT, J1OFF, s19);
    V3 e22 = fk_end(J2OFF, s20);
    V3 e23 = fk_end(J3OFF, s21);

    // ---- exchange B results; s_eeB aliases s_off -> barrier BEFORE writes ----
    __syncthreads();
    if (isB) {
        float* eb = s_eeB + fl * 15;       // stride 15 floats, coprime 32: no conflict
        eb[ 0] = e10.x; eb[ 1] = e10.y; eb[ 2] = e10.z;
        eb[ 3] = e11.x; eb[ 4] = e11.y; eb[ 5] = e11.z;
        eb[ 6] = e15.x; eb[ 7] = e15.y; eb[ 8] = e15.z;
        eb[ 9] = e22.x; eb[10] = e22.y; eb[11] = e22.z;
        eb[12] = e23.x; eb[13] = e23.y; eb[14] = e23.z;
    }
    __syncthreads();

    float local = 0.0f;
    if (!isB) {
        const float iax = s_inv[0], iay = s_inv[1], iaz = s_inv[2];
        const float ibx = s_inv[3], iby = s_inv[4], ibz = s_inv[5];
        const float* eb = s_eeB + fl * 15;
        float t0  = e10.x*iax - eb[ 0]*ibx + s_d[ 0];
        float t1  = e10.y*iay - eb[ 1]*iby + s_d[ 1];
        float t2  = e10.z*iaz - eb[ 2]*ibz + s_d[ 2];
        float t3  = e11.x*iax - eb[ 3]*ibx + s_d[ 3];
        float t4  = e11.y*iay - eb[ 4]*iby + s_d[ 4];
        float t5  = e11.z*iaz - eb[ 5]*ibz + s_d[ 5];
        float t6  = e15.x*iax - eb[ 6]*ibx + s_d[ 6];
        float t7  = e15.y*iay - eb[ 7]*iby + s_d[ 7];
        float t8  = e15.z*iaz - eb[ 8]*ibz + s_d[ 8];
        float t9  = e22.x*iax - eb[ 9]*ibx + s_d[ 9];
        float t10 = e22.y*iay - eb[10]*iby + s_d[10];
        float t11 = e22.z*iaz - eb[11]*ibz + s_d[11];
        float t12 = e23.x*iax - eb[12]*ibx + s_d[12];
        float t13 = e23.y*iay - eb[13]*iby + s_d[13];
        float t14 = e23.z*iaz - eb[14]*ibz + s_d[14];
        local = ((t0*t0 + t1*t1) + (t2*t2 + t3*t3) + (t4*t4 + t5*t5) +
                 (t6*t6 + t7*t7) + (t8*t8 + t9*t9) + (t10*t10 + t11*t11) +
                 (t12*t12 + t13*t13) + t14*t14) * inv_count;
#pragma unroll
        for (int off = 32; off > 0; off >>= 1)
            local += __shfl_down(local, off, 64);
        if (lane == 0) s_part[fg] = local;
    }
    __syncthreads();
    if (tid == 0) atomicAdd(out, s_part[0] + s_part[1]);
}

extern "C" void kernel_launch(void* const* d_in, const int* in_sizes, int n_in,
                              void* d_out, int out_size, void* d_ws, size_t ws_size,
                              hipStream_t stream) {
    const float* poseA = (const float*)d_in[0];
    const float* poseB = (const float*)d_in[1];
    const float* offA  = (const float*)d_in[2];
    const float* offB  = (const float*)d_in[3];
    const float* tA    = (const float*)d_in[4];
    const float* tB    = (const float*)d_in[5];
    float* out = (float*)d_out;

    const int F = in_sizes[0] / 144;          // 65536
    const int blocks = F / 128;               // 512 = 2 blocks/CU exactly
    const float inv_count = 1.0f / ((float)F * 15.0f);

    hipMemsetAsync(out, 0, sizeof(float), stream);
    ee_loss_kernel<<<blocks, 256, 0, stream>>>(poseA, poseB, offA, offB, tA, tB,
                                               out, inv_count);
}